// Round 13
// baseline (855.695 us; speedup 1.0000x reference)
//
#include <hip/hip_runtime.h>
#include <math.h>

#define NN 50000      // nodes
#define NE 800000     // edges
#define NP 200000     // link pairs
#define NF 128        // feature dim
#define NEDGE_TOT (NE + NN)   // edges + self loops
#define NBLK 196              // ceil(NN/256)
#define NBK 64                // dst-range buckets
#define DPB 782               // dsts per bucket
#define BKCAP 16384           // bucket capacity
#define EPB 2048              // edges per Phase-A block
#define CROWS ((size_t)(NN + 1) * 32)   // elems per chunk incl. zero dummy row
#define NODEBLK 3128                    // ceil(50048/16) node-blocks per chunk
#define GSTEPC (8 * ((NODEBLK + 1) / 2))  // swizzled grid: 12512 blocks

typedef __attribute__((ext_vector_type(8))) short short8;
typedef __attribute__((ext_vector_type(4))) float float4v;
typedef __attribute__((ext_vector_type(2))) _Float16 h2;

// ---- bf16 helpers (manual, RNE) ----
__device__ __forceinline__ float bf_lo(unsigned u) { return __uint_as_float(u << 16); }
__device__ __forceinline__ float bf_hi(unsigned u) { return __uint_as_float(u & 0xffff0000u); }
__device__ __forceinline__ unsigned short f2bf(float f) {
    unsigned u = __float_as_uint(f);
    return (unsigned short)((u + 0x7fffu + ((u >> 16) & 1u)) >> 16);
}
__device__ __forceinline__ unsigned pack2bf(float a, float b) {
    return (unsigned)f2bf(a) | ((unsigned)f2bf(b) << 16);
}

// ---- f16 helpers ----
__device__ __forceinline__ h2 u2h2(unsigned u) {
    union { unsigned u; h2 h; } c; c.u = u; return c.h;
}
__device__ __forceinline__ unsigned h22u(h2 h) {
    union { unsigned u; h2 h; } c; c.h = h; return c.u;
}
__device__ __forceinline__ float h_lo(unsigned u) { return (float)u2h2(u).x; }
__device__ __forceinline__ float h_hi(unsigned u) { return (float)u2h2(u).y; }
__device__ __forceinline__ unsigned pack2h(float a, float b) {
    h2 h; h.x = (_Float16)a; h.y = (_Float16)b; return h22u(h);
}

// ---------------------------------------------------------------------------
// degree count + scan (row_ptr, dinv)
// ---------------------------------------------------------------------------
__global__ __launch_bounds__(256) void init_cnt_k(int* __restrict__ cnt) {
    int i = blockIdx.x * 256 + threadIdx.x;
    if (i < NN) cnt[i] = 1;  // self-loop
}

__global__ __launch_bounds__(256) void count_k(const int* __restrict__ ei,
                                               int* __restrict__ cnt) {
    int e = blockIdx.x * 256 + threadIdx.x;
    if (e < NE) atomicAdd(&cnt[ei[NE + e]], 1);
}

__global__ __launch_bounds__(256) void scan_reduce_k(const int* __restrict__ cnt,
                                                     int* __restrict__ bsum,
                                                     float* __restrict__ dinv) {
    __shared__ int s[256];
    int t = threadIdx.x;
    int idx = blockIdx.x * 256 + t;
    int v = (idx < NN) ? cnt[idx] : 0;
    if (idx < NN) dinv[idx] = rsqrtf((float)v);
    s[t] = v;
    __syncthreads();
    for (int off = 128; off > 0; off >>= 1) {
        if (t < off) s[t] += s[t + off];
        __syncthreads();
    }
    if (t == 0) bsum[blockIdx.x] = s[0];
}

__global__ __launch_bounds__(256) void scan_bsums_k(const int* __restrict__ bsum,
                                                    int* __restrict__ boff) {
    __shared__ int s[256];
    int t = threadIdx.x;
    int v = (t < NBLK) ? bsum[t] : 0;
    s[t] = v;
    __syncthreads();
    for (int off = 1; off < 256; off <<= 1) {
        int add = (t >= off) ? s[t - off] : 0;
        __syncthreads();
        s[t] += add;
        __syncthreads();
    }
    if (t < NBLK) boff[t] = s[t] - v;
}

__global__ __launch_bounds__(256) void scan_down_k(const int* __restrict__ cnt,
                                                   const int* __restrict__ boff,
                                                   int* __restrict__ row_ptr) {
    __shared__ int s[256];
    int t = threadIdx.x;
    int idx = blockIdx.x * 256 + t;
    int v = (idx < NN) ? cnt[idx] : 0;
    s[t] = v;
    __syncthreads();
    for (int off = 1; off < 256; off <<= 1) {
        int add = (t >= off) ? s[t - off] : 0;
        __syncthreads();
        s[t] += add;
        __syncthreads();
    }
    int excl = s[t] - v + boff[blockIdx.x];
    if (idx < NN) {
        row_ptr[idx] = excl;
        if (idx == NN - 1) row_ptr[NN] = excl + v;
    }
}

// ---------------------------------------------------------------------------
// Two-phase binned CSR build (round 8, verified).
// ---------------------------------------------------------------------------
__global__ __launch_bounds__(256) void bin_k(const int* __restrict__ ei,
                                             int* __restrict__ gtail,
                                             int2* __restrict__ gbk) {
    __shared__ int cntA[NBK], baseA[NBK], gposA[NBK];
    __shared__ int2 stage[EPB];
    int tid = threadIdx.x;
    int ebase = blockIdx.x * EPB;
    int sv[8], dv[8], lp8[8], bk8[8];
    bool val[8];
    if (tid < NBK) cntA[tid] = 0;
    __syncthreads();
#pragma unroll
    for (int k = 0; k < 8; ++k) {
        int e = ebase + k * 256 + tid;
        val[k] = (e < NEDGE_TOT);
        if (val[k]) {
            int s, d;
            if (e < NE) { s = ei[e]; d = ei[NE + e]; }
            else        { s = d = e - NE; }
            sv[k] = s; dv[k] = d;
            bk8[k] = d / DPB;
            lp8[k] = atomicAdd(&cntA[bk8[k]], 1);
        }
    }
    __syncthreads();
    if (tid == 0) {
        int run = 0;
        for (int b = 0; b < NBK; ++b) { baseA[b] = run; run += cntA[b]; }
    }
    __syncthreads();
    if (tid < NBK && cntA[tid] > 0)
        gposA[tid] = atomicAdd(&gtail[tid], cntA[tid]);
    __syncthreads();
#pragma unroll
    for (int k = 0; k < 8; ++k)
        if (val[k]) {
            int2 r; r.x = sv[k]; r.y = dv[k];
            stage[baseA[bk8[k]] + lp8[k]] = r;
        }
    __syncthreads();
    int total = baseA[NBK - 1] + cntA[NBK - 1];
    for (int i = tid; i < total; i += 256) {
        int2 r = stage[i];
        int b = r.y / DPB;
        gbk[(size_t)b * BKCAP + gposA[b] + (i - baseA[b])] = r;
    }
}

__global__ __launch_bounds__(256) void build_k(const int* __restrict__ row_ptr,
                                               const int* __restrict__ gtail,
                                               const int2* __restrict__ gbk,
                                               int* __restrict__ cols) {
    __shared__ int wcur[DPB];
    int tid = threadIdx.x;
    int b = blockIdx.x;
    int d0 = b * DPB;
    for (int i = tid; i < DPB; i += 256) {
        int d = d0 + i;
        wcur[i] = (d < NN) ? row_ptr[d] : 0;
    }
    __syncthreads();
    int nb = gtail[b];
    const int2* src = gbk + (size_t)b * BKCAP;
    for (int t = tid; t < nb; t += 256) {
        int2 r = src[t];
        int pos = atomicAdd(&wcur[r.y - d0], 1);
        cols[pos] = r.x;
    }
}

// zero dummy row NN in all 4 chunks of the four state buffers + bucket tails
__global__ __launch_bounds__(256) void zero_k(unsigned short* Ys1, unsigned short* Ys2,
                                              unsigned short* HA, unsigned short* HB,
                                              int* gtail) {
    int t = threadIdx.x;  // 256 = 4 bufs x 4 chunks x 16 uints
    unsigned short* bufs[4] = {Ys1, Ys2, HA, HB};
    unsigned short* b = bufs[t >> 6];
    int chunk = (t >> 4) & 3;
    ((unsigned*)(b + (size_t)chunk * CROWS + (size_t)NN * 32))[t & 15] = 0u;
    if (t < NBK) gtail[t] = 0;
}

// W fp32 -> bf16 row-major
__global__ __launch_bounds__(256) void cast_w_k(const float* __restrict__ W,
                                                unsigned short* __restrict__ Wb) {
    int t = blockIdx.x * 256 + threadIdx.x;
    if (t >= 128 * 128 / 8) return;
    int i = t * 8;
    float4 f0 = *(const float4*)(W + i);
    float4 f1 = *(const float4*)(W + i + 4);
    uint4 q;
    q.x = pack2bf(f0.x, f0.y);
    q.y = pack2bf(f0.z, f0.w);
    q.z = pack2bf(f1.x, f1.y);
    q.w = pack2bf(f1.z, f1.w);
    *(uint4*)(Wb + i) = q;
}

// ---------------------------------------------------------------------------
// MFMA GEMM (verified bf16 fragment layouts, rounds 2-12): Y = X @ W.T + b.
// F32IN: X = input x, fp32 row-major. Else: X = Hrelu, bf16 CHUNK-MAJOR
// [4][NN+1][32] (A-frag read per chunk, the r2-verified pattern).
// Dual CHUNK-MAJOR f16 epilogue: Yu unscaled (x0 stream), Ys dinv-scaled hs0.
// ---------------------------------------------------------------------------
#define GPAD 136
template <bool F32IN>
__global__ __launch_bounds__(256) void gemm_mfma_k(const void* __restrict__ Xv,
                                                   const unsigned short* __restrict__ Wb,
                                                   const float* __restrict__ bias,
                                                   const float* __restrict__ dinv,
                                                   unsigned short* __restrict__ Yu,
                                                   unsigned short* __restrict__ Ys,
                                                   int nrows) {
    __shared__ unsigned short sm[4 * 16 * GPAD];  // 17408 B
    int wave = threadIdx.x >> 6, lane = threadIdx.x & 63;
    int rbase = blockIdx.x * 64 + wave * 16;
    if (rbase >= nrows) return;
    int quad = lane >> 4, mn = lane & 15;
    float4v acc[8];
#pragma unroll
    for (int ft = 0; ft < 8; ++ft) acc[ft] = (float4v){0.f, 0.f, 0.f, 0.f};
#pragma unroll
    for (int kb = 0; kb < 128; kb += 32) {
        short8 a;
        if (F32IN) {
            const float* X = (const float*)Xv;
            float4 f0 = *(const float4*)(X + (size_t)(rbase + mn) * NF + kb + quad * 8);
            float4 f1 = *(const float4*)(X + (size_t)(rbase + mn) * NF + kb + quad * 8 + 4);
            a[0] = (short)f2bf(f0.x); a[1] = (short)f2bf(f0.y);
            a[2] = (short)f2bf(f0.z); a[3] = (short)f2bf(f0.w);
            a[4] = (short)f2bf(f1.x); a[5] = (short)f2bf(f1.y);
            a[6] = (short)f2bf(f1.z); a[7] = (short)f2bf(f1.w);
        } else {
            const unsigned short* X = (const unsigned short*)Xv;
            a = *(const short8*)(X + (size_t)(kb >> 5) * CROWS +
                                (size_t)(rbase + mn) * 32 + quad * 8);
        }
#pragma unroll
        for (int ft = 0; ft < 8; ++ft) {
            short8 b = *(const short8*)(Wb + (size_t)(ft * 16 + mn) * NF + kb + quad * 8);
            acc[ft] = __builtin_amdgcn_mfma_f32_16x16x32_bf16(a, b, acc[ft], 0, 0, 0);
        }
    }
    unsigned short* smw = sm + wave * 16 * GPAD;
#pragma unroll
    for (int ft = 0; ft < 8; ++ft) {
        float bv = bias[ft * 16 + mn];
#pragma unroll
        for (int r = 0; r < 4; ++r) {
            union { _Float16 h; unsigned short s; } cv;
            cv.h = (_Float16)(acc[ft][r] + bv);
            smw[(quad * 4 + r) * GPAD + ft * 16 + mn] = cv.s;
        }
    }
    __syncthreads();
#pragma unroll
    for (int t = 0; t < 4; ++t) {
        int rl = t * 4 + quad;
        int row = rbase + rl;
        uint4 q = *(const uint4*)(smw + rl * GPAD + mn * 8);  // f = mn*8..+7
        size_t dst = (size_t)(mn >> 2) * CROWS + (size_t)row * 32 + (mn & 3) * 8;
        *(uint4*)(Yu + dst) = q;
        float g = dinv[row];
        uint4 qs;
        qs.x = pack2h(g * h_lo(q.x), g * h_hi(q.x));
        qs.y = pack2h(g * h_lo(q.y), g * h_hi(q.y));
        qs.z = pack2h(g * h_lo(q.z), g * h_hi(q.z));
        qs.w = pack2h(g * h_lo(q.w), g * h_hi(q.w));
        *(uint4*)(Ys + dst) = qs;
    }
}

// ---------------------------------------------------------------------------
// XCD-affine chunked APPNP step. State chunk-major f16 [4][NN+1][32].
// blockIdx%8 selects the chunk PAIR-wise: chunk = (blockIdx%8)>>1, so (if
// workgroups round-robin XCDs by blockIdx%8) chunk c lives ONLY on XCDs
// {2c,2c+1}: its 3.2 MB state fits a 4 MB L2, writes stay local, and next
// step's gathers re-hit the same pair's L2s -> kills the 90 MB/step
// cross-XCD refill measured in r11/r12.
// One 16-lane group per node (16 nodes/block); lane li owns feats li*2,li*2+1
// exclusively -> NO cross-lane reduction. 4 gathers (4 B/lane, 64 B row) in
// flight; round-up-4 windows gather the zeroed dummy row NN.
//   A = sum_e hs_c[col_e]; h_new = 0.9*dinv*A + 0.1*x0_c
//   mode 0: out = dinv*h_new (f16 chunk)  mode 1: relu -> bf16 chunk (GEMM2)
//   mode 2: relu + partial pair projection -> puvP[node*4+chunk]
// ---------------------------------------------------------------------------
__global__ __launch_bounds__(256) void appnp_c2_k(const unsigned short* __restrict__ hs,
                                                  const unsigned short* __restrict__ x0c,
                                                  const float* __restrict__ dinv,
                                                  unsigned short* __restrict__ out,
                                                  const int* __restrict__ row_ptr,
                                                  const int* __restrict__ cols,
                                                  int mode,
                                                  const float* __restrict__ W3,
                                                  float4* __restrict__ puvP) {
    int bid8 = blockIdx.x & 7;
    int chunk = bid8 >> 1;
    int nodeBlk = (blockIdx.x >> 3) * 2 + (bid8 & 1);
    int grp = threadIdx.x >> 4;
    int li = threadIdx.x & 15;
    int node = nodeBlk * 16 + grp;
    if (node >= NN) return;
    int gb = (threadIdx.x & 63) & ~15;  // group base lane within wave
    const unsigned short* hc = hs + (size_t)chunk * CROWS;
    int beg = row_ptr[node], end = row_ptr[node + 1];
    h2 acc; acc.x = (_Float16)0.f; acc.y = (_Float16)0.f;
    for (int e = beg; e < end; e += 16) {
        int m = end - e;
        if (m > 16) m = 16;
        int c = (li < m) ? cols[e + li] : NN;  // NN = zero row
        for (int j = 0; j < m; j += 4) {
            int c0 = __shfl(c, gb + j, 64);
            int c1 = __shfl(c, gb + j + 1, 64);
            int c2 = __shfl(c, gb + j + 2, 64);
            int c3 = __shfl(c, gb + j + 3, 64);
            unsigned q0 = *(const unsigned*)(hc + (size_t)c0 * 32 + li * 2);
            unsigned q1 = *(const unsigned*)(hc + (size_t)c1 * 32 + li * 2);
            unsigned q2 = *(const unsigned*)(hc + (size_t)c2 * 32 + li * 2);
            unsigned q3 = *(const unsigned*)(hc + (size_t)c3 * 32 + li * 2);
            acc += (u2h2(q0) + u2h2(q1)) + (u2h2(q2) + u2h2(q3));
        }
    }
    float g = dinv[node];
    float s9 = 0.9f * g;
    unsigned xq = *(const unsigned*)(x0c + (size_t)chunk * CROWS + (size_t)node * 32 + li * 2);
    float h0 = s9 * (float)acc.x + 0.1f * h_lo(xq);
    float h1 = s9 * (float)acc.y + 0.1f * h_hi(xq);
    size_t oidx = (size_t)chunk * CROWS + (size_t)node * 32 + li * 2;
    if (mode == 0) {
        *(unsigned*)(out + oidx) = pack2h(g * h0, g * h1);
    } else {
        h0 = fmaxf(h0, 0.f);
        h1 = fmaxf(h1, 0.f);
        if (mode == 1) {
            *(unsigned*)(out + oidx) = pack2bf(h0, h1);
        } else {
            int f = chunk * 32 + li * 2;
            float du0 = h0 * W3[f] + h1 * W3[f + 1];
            float du1 = h0 * W3[256 + f] + h1 * W3[256 + f + 1];
            float dv0 = h0 * W3[128 + f] + h1 * W3[128 + f + 1];
            float dv1 = h0 * W3[384 + f] + h1 * W3[384 + f + 1];
#pragma unroll
            for (int off = 1; off < 16; off <<= 1) {
                du0 += __shfl_xor(du0, off, 64);
                du1 += __shfl_xor(du1, off, 64);
                dv0 += __shfl_xor(dv0, off, 64);
                dv1 += __shfl_xor(dv1, off, 64);
            }
            if (li == 0) puvP[(size_t)node * 4 + chunk] = make_float4(du0, du1, dv0, dv1);
        }
    }
}

// ---------------------------------------------------------------------------
// Pair head: sums the 4 per-chunk partial projections; one thread per pair.
// ---------------------------------------------------------------------------
__global__ __launch_bounds__(256) void pair2_k(const float4* __restrict__ puvP,
                                               const int2* __restrict__ index,
                                               const float* __restrict__ b3,
                                               float* __restrict__ outp) {
    int p = blockIdx.x * 256 + threadIdx.x;
    if (p >= NP) return;
    int2 uv = index[p];
    float s0 = b3[0], s1 = b3[1];
#pragma unroll
    for (int c = 0; c < 4; ++c) {
        float4 a = puvP[(size_t)uv.x * 4 + c];
        float4 b = puvP[(size_t)uv.y * 4 + c];
        s0 += a.x + b.z;
        s1 += a.y + b.w;
    }
    float m = fmaxf(s0, s1);
    float lse = m + logf(expf(s0 - m) + expf(s1 - m));
    *(float2*)(outp + (size_t)p * 2) = make_float2(s0 - lse, s1 - lse);
}

// ---------------------------------------------------------------------------
// Launch
// ---------------------------------------------------------------------------
extern "C" void kernel_launch(void* const* d_in, const int* in_sizes, int n_in,
                              void* d_out, int out_size, void* d_ws, size_t ws_size,
                              hipStream_t stream) {
    const float* x  = (const float*)d_in[0];
    const int* ei   = (const int*)d_in[1];
    const int* idx  = (const int*)d_in[2];
    const float* W1 = (const float*)d_in[3];
    const float* b1 = (const float*)d_in[4];
    const float* W2 = (const float*)d_in[5];
    const float* b2 = (const float*)d_in[6];
    const float* W3 = (const float*)d_in[7];
    const float* b3 = (const float*)d_in[8];
    float* out = (float*)d_out;

    char* ws = (char*)d_ws;
    size_t off = 0;
    auto alloc = [&](size_t bytes) -> void* {
        void* p = ws + off;
        off = (off + bytes + 255) & ~(size_t)255;
        return p;
    };
    const size_t HBYTES = 4 * CROWS * 2;  // chunk-major f16/bf16 buffer bytes
    int*   cnt     = (int*)  alloc(NN * sizeof(int));
    float* dinv    = (float*)alloc(NN * sizeof(float));
    int*   row_ptr = (int*)  alloc((NN + 1) * sizeof(int));
    int*   bsum    = (int*)  alloc(NBLK * sizeof(int));
    int*   boff    = (int*)  alloc(NBLK * sizeof(int));
    int*   gtail   = (int*)  alloc(NBK * sizeof(int));
    int2*  gbk     = (int2*) alloc((size_t)NBK * BKCAP * sizeof(int2));  // 8 MB
    int*   cols    = (int*)  alloc((size_t)NEDGE_TOT * sizeof(int));
    float4* puvP   = (float4*)alloc((size_t)NN * 4 * sizeof(float4));
    unsigned short* Wb1 = (unsigned short*)alloc(128 * 128 * 2);
    unsigned short* Wb2 = (unsigned short*)alloc(128 * 128 * 2);
    unsigned short* Yu1 = (unsigned short*)alloc(HBYTES);
    unsigned short* Ys1 = (unsigned short*)alloc(HBYTES);
    unsigned short* Yu2 = (unsigned short*)alloc(HBYTES);
    unsigned short* Ys2 = (unsigned short*)alloc(HBYTES);
    unsigned short* HA  = (unsigned short*)alloc(HBYTES);
    unsigned short* HB  = (unsigned short*)alloc(HBYTES);
    unsigned short* Hrelu = (unsigned short*)alloc(HBYTES);

    const int gN    = (NN + 255) / 256;
    const int gE    = (NE + 255) / 256;
    const int gBin  = (NEDGE_TOT + EPB - 1) / EPB;
    const int gGemm = (NN + 63) / 64;            // wave per 16 rows
    const int gPair = (NP + 255) / 256;          // thread per pair

    // ---- weights + gcn_norm + binned CSR ----
    cast_w_k<<<8, 256, 0, stream>>>(W1, Wb1);
    cast_w_k<<<8, 256, 0, stream>>>(W2, Wb2);
    zero_k<<<1, 256, 0, stream>>>(Ys1, Ys2, HA, HB, gtail);
    init_cnt_k<<<gN, 256, 0, stream>>>(cnt);
    count_k<<<gE, 256, 0, stream>>>(ei, cnt);
    scan_reduce_k<<<NBLK, 256, 0, stream>>>(cnt, bsum, dinv);
    scan_bsums_k<<<1, 256, 0, stream>>>(bsum, boff);
    scan_down_k<<<NBLK, 256, 0, stream>>>(cnt, boff, row_ptr);
    bin_k<<<gBin, 256, 0, stream>>>(ei, gtail, gbk);
    build_k<<<NBK, 256, 0, stream>>>(row_ptr, gtail, gbk, cols);

    // ---- layer 1 ----
    gemm_mfma_k<true><<<gGemm, 256, 0, stream>>>(x, Wb1, b1, dinv, Yu1, Ys1, NN);
    {
        const unsigned short* cur = Ys1;
        for (int k = 0; k < 10; ++k) {
            unsigned short* dst = (k == 9) ? Hrelu : ((k & 1) ? HB : HA);
            appnp_c2_k<<<GSTEPC, 256, 0, stream>>>(cur, Yu1, dinv, dst, row_ptr,
                                                   cols, (k == 9) ? 1 : 0, W3, puvP);
            cur = dst;
        }
    }
    // ---- layer 2 ----
    gemm_mfma_k<false><<<gGemm, 256, 0, stream>>>(Hrelu, Wb2, b2, dinv, Yu2, Ys2, NN);
    {
        const unsigned short* cur = Ys2;
        for (int k = 0; k < 10; ++k) {
            unsigned short* dst = (k & 1) ? HB : HA;
            appnp_c2_k<<<GSTEPC, 256, 0, stream>>>(cur, Yu2, dinv, dst, row_ptr,
                                                   cols, (k == 9) ? 2 : 0, W3, puvP);
            cur = dst;
        }
    }
    // ---- pair head ----
    pair2_k<<<gPair, 256, 0, stream>>>(puvP, (const int2*)idx, b3, out);
}

// Round 14
// 828.108 us; speedup vs baseline: 1.0333x; 1.0333x over previous
//
#include <hip/hip_runtime.h>
#include <math.h>

#define NN 50000      // nodes
#define NE 800000     // edges
#define NP 200000     // link pairs
#define NF 128        // feature dim
#define NEDGE_TOT (NE + NN)   // edges + self loops
#define NBLK 196              // ceil(NN/256)
#define NBK 64                // dst-range buckets
#define DPB 782               // dsts per bucket
#define BKCAP 16384           // bucket capacity
#define EPB 2048              // edges per Phase-A block

typedef __attribute__((ext_vector_type(8))) short short8;
typedef __attribute__((ext_vector_type(4))) float float4v;
typedef __attribute__((ext_vector_type(2))) _Float16 h2;

// ---- bf16 helpers (manual, RNE) ----
__device__ __forceinline__ float bf_lo(unsigned u) { return __uint_as_float(u << 16); }
__device__ __forceinline__ float bf_hi(unsigned u) { return __uint_as_float(u & 0xffff0000u); }
__device__ __forceinline__ unsigned short f2bf(float f) {
    unsigned u = __float_as_uint(f);
    return (unsigned short)((u + 0x7fffu + ((u >> 16) & 1u)) >> 16);
}
__device__ __forceinline__ unsigned pack2bf(float a, float b) {
    return (unsigned)f2bf(a) | ((unsigned)f2bf(b) << 16);
}

// ---- f16 helpers ----
__device__ __forceinline__ h2 u2h2(unsigned u) {
    union { unsigned u; h2 h; } c; c.u = u; return c.h;
}
__device__ __forceinline__ unsigned h22u(h2 h) {
    union { unsigned u; h2 h; } c; c.h = h; return c.u;
}
__device__ __forceinline__ float h_lo(unsigned u) { return (float)u2h2(u).x; }
__device__ __forceinline__ float h_hi(unsigned u) { return (float)u2h2(u).y; }
__device__ __forceinline__ unsigned pack2h(float a, float b) {
    h2 h; h.x = (_Float16)a; h.y = (_Float16)b; return h22u(h);
}

// ---------------------------------------------------------------------------
// degree count + scan (row_ptr, dinv)
// ---------------------------------------------------------------------------
__global__ __launch_bounds__(256) void init_cnt_k(int* __restrict__ cnt) {
    int i = blockIdx.x * 256 + threadIdx.x;
    if (i < NN) cnt[i] = 1;  // self-loop
}

__global__ __launch_bounds__(256) void count_k(const int* __restrict__ ei,
                                               int* __restrict__ cnt) {
    int e = blockIdx.x * 256 + threadIdx.x;
    if (e < NE) atomicAdd(&cnt[ei[NE + e]], 1);
}

__global__ __launch_bounds__(256) void scan_reduce_k(const int* __restrict__ cnt,
                                                     int* __restrict__ bsum,
                                                     float* __restrict__ dinv) {
    __shared__ int s[256];
    int t = threadIdx.x;
    int idx = blockIdx.x * 256 + t;
    int v = (idx < NN) ? cnt[idx] : 0;
    if (idx < NN) dinv[idx] = rsqrtf((float)v);
    s[t] = v;
    __syncthreads();
    for (int off = 128; off > 0; off >>= 1) {
        if (t < off) s[t] += s[t + off];
        __syncthreads();
    }
    if (t == 0) bsum[blockIdx.x] = s[0];
}

__global__ __launch_bounds__(256) void scan_bsums_k(const int* __restrict__ bsum,
                                                    int* __restrict__ boff) {
    __shared__ int s[256];
    int t = threadIdx.x;
    int v = (t < NBLK) ? bsum[t] : 0;
    s[t] = v;
    __syncthreads();
    for (int off = 1; off < 256; off <<= 1) {
        int add = (t >= off) ? s[t - off] : 0;
        __syncthreads();
        s[t] += add;
        __syncthreads();
    }
    if (t < NBLK) boff[t] = s[t] - v;
}

__global__ __launch_bounds__(256) void scan_down_k(const int* __restrict__ cnt,
                                                   const int* __restrict__ boff,
                                                   int* __restrict__ row_ptr) {
    __shared__ int s[256];
    int t = threadIdx.x;
    int idx = blockIdx.x * 256 + t;
    int v = (idx < NN) ? cnt[idx] : 0;
    s[t] = v;
    __syncthreads();
    for (int off = 1; off < 256; off <<= 1) {
        int add = (t >= off) ? s[t - off] : 0;
        __syncthreads();
        s[t] += add;
        __syncthreads();
    }
    int excl = s[t] - v + boff[blockIdx.x];
    if (idx < NN) {
        row_ptr[idx] = excl;
        if (idx == NN - 1) row_ptr[NN] = excl + v;
    }
}

// ---------------------------------------------------------------------------
// Two-phase binned CSR build (round 8, verified).
// ---------------------------------------------------------------------------
__global__ __launch_bounds__(256) void bin_k(const int* __restrict__ ei,
                                             int* __restrict__ gtail,
                                             int2* __restrict__ gbk) {
    __shared__ int cntA[NBK], baseA[NBK], gposA[NBK];
    __shared__ int2 stage[EPB];
    int tid = threadIdx.x;
    int ebase = blockIdx.x * EPB;
    int sv[8], dv[8], lp8[8], bk8[8];
    bool val[8];
    if (tid < NBK) cntA[tid] = 0;
    __syncthreads();
#pragma unroll
    for (int k = 0; k < 8; ++k) {
        int e = ebase + k * 256 + tid;
        val[k] = (e < NEDGE_TOT);
        if (val[k]) {
            int s, d;
            if (e < NE) { s = ei[e]; d = ei[NE + e]; }
            else        { s = d = e - NE; }
            sv[k] = s; dv[k] = d;
            bk8[k] = d / DPB;
            lp8[k] = atomicAdd(&cntA[bk8[k]], 1);
        }
    }
    __syncthreads();
    if (tid == 0) {
        int run = 0;
        for (int b = 0; b < NBK; ++b) { baseA[b] = run; run += cntA[b]; }
    }
    __syncthreads();
    if (tid < NBK && cntA[tid] > 0)
        gposA[tid] = atomicAdd(&gtail[tid], cntA[tid]);
    __syncthreads();
#pragma unroll
    for (int k = 0; k < 8; ++k)
        if (val[k]) {
            int2 r; r.x = sv[k]; r.y = dv[k];
            stage[baseA[bk8[k]] + lp8[k]] = r;
        }
    __syncthreads();
    int total = baseA[NBK - 1] + cntA[NBK - 1];
    for (int i = tid; i < total; i += 256) {
        int2 r = stage[i];
        int b = r.y / DPB;
        gbk[(size_t)b * BKCAP + gposA[b] + (i - baseA[b])] = r;
    }
}

__global__ __launch_bounds__(256) void build_k(const int* __restrict__ row_ptr,
                                               const int* __restrict__ gtail,
                                               const int2* __restrict__ gbk,
                                               int* __restrict__ cols) {
    __shared__ int wcur[DPB];
    int tid = threadIdx.x;
    int b = blockIdx.x;
    int d0 = b * DPB;
    for (int i = tid; i < DPB; i += 256) {
        int d = d0 + i;
        wcur[i] = (d < NN) ? row_ptr[d] : 0;
    }
    __syncthreads();
    int nb = gtail[b];
    const int2* src = gbk + (size_t)b * BKCAP;
    for (int t = tid; t < nb; t += 256) {
        int2 r = src[t];
        int pos = atomicAdd(&wcur[r.y - d0], 1);
        cols[pos] = r.x;
    }
}

// zero dummy rows (row NN) of the four f16 state buffers + bucket tails
__global__ __launch_bounds__(256) void zero_k(unsigned short* Ys1, unsigned short* Ys2,
                                              unsigned short* HA, unsigned short* HB,
                                              int* gtail) {
    int t = threadIdx.x;  // 256 threads; 4 rows x 64 uints
    unsigned short* bufs[4] = {Ys1, Ys2, HA, HB};
    unsigned short* b = bufs[t >> 6];
    ((unsigned*)(b + (size_t)NN * NF))[t & 63] = 0u;
    if (t < NBK) gtail[t] = 0;
}

// W fp32 -> bf16 row-major (GEMM B operand stays on verified bf16 MFMA path)
__global__ __launch_bounds__(256) void cast_w_k(const float* __restrict__ W,
                                                unsigned short* __restrict__ Wb) {
    int t = blockIdx.x * 256 + threadIdx.x;
    if (t >= 128 * 128 / 8) return;
    int i = t * 8;
    float4 f0 = *(const float4*)(W + i);
    float4 f1 = *(const float4*)(W + i + 4);
    uint4 q;
    q.x = pack2bf(f0.x, f0.y);
    q.y = pack2bf(f0.z, f0.w);
    q.z = pack2bf(f1.x, f1.y);
    q.w = pack2bf(f1.z, f1.w);
    *(uint4*)(Wb + i) = q;
}

// ---------------------------------------------------------------------------
// MFMA GEMM (verified bf16 fragment layouts, rounds 2-13): Y = X @ W.T + b.
// Dual f16 epilogue: Yu = unscaled f16 (x0 stream), Ys = dinv-scaled f16 hs0.
// ---------------------------------------------------------------------------
#define GPAD 136
template <bool F32IN>
__global__ __launch_bounds__(256) void gemm_mfma_k(const void* __restrict__ Xv,
                                                   const unsigned short* __restrict__ Wb,
                                                   const float* __restrict__ bias,
                                                   const float* __restrict__ dinv,
                                                   unsigned short* __restrict__ Yu,
                                                   unsigned short* __restrict__ Ys,
                                                   int nrows) {
    __shared__ unsigned short sm[4 * 16 * GPAD];  // 17408 B
    int wave = threadIdx.x >> 6, lane = threadIdx.x & 63;
    int rbase = blockIdx.x * 64 + wave * 16;
    if (rbase >= nrows) return;
    int quad = lane >> 4, mn = lane & 15;
    float4v acc[8];
#pragma unroll
    for (int ft = 0; ft < 8; ++ft) acc[ft] = (float4v){0.f, 0.f, 0.f, 0.f};
#pragma unroll
    for (int kb = 0; kb < 128; kb += 32) {
        short8 a;
        if (F32IN) {
            const float* X = (const float*)Xv;
            float4 f0 = *(const float4*)(X + (size_t)(rbase + mn) * NF + kb + quad * 8);
            float4 f1 = *(const float4*)(X + (size_t)(rbase + mn) * NF + kb + quad * 8 + 4);
            a[0] = (short)f2bf(f0.x); a[1] = (short)f2bf(f0.y);
            a[2] = (short)f2bf(f0.z); a[3] = (short)f2bf(f0.w);
            a[4] = (short)f2bf(f1.x); a[5] = (short)f2bf(f1.y);
            a[6] = (short)f2bf(f1.z); a[7] = (short)f2bf(f1.w);
        } else {
            const unsigned short* X = (const unsigned short*)Xv;
            a = *(const short8*)(X + (size_t)(rbase + mn) * NF + kb + quad * 8);
        }
#pragma unroll
        for (int ft = 0; ft < 8; ++ft) {
            short8 b = *(const short8*)(Wb + (size_t)(ft * 16 + mn) * NF + kb + quad * 8);
            acc[ft] = __builtin_amdgcn_mfma_f32_16x16x32_bf16(a, b, acc[ft], 0, 0, 0);
        }
    }
    unsigned short* smw = sm + wave * 16 * GPAD;
#pragma unroll
    for (int ft = 0; ft < 8; ++ft) {
        float bv = bias[ft * 16 + mn];
#pragma unroll
        for (int r = 0; r < 4; ++r) {
            union { _Float16 h; unsigned short s; } cv;
            cv.h = (_Float16)(acc[ft][r] + bv);
            smw[(quad * 4 + r) * GPAD + ft * 16 + mn] = cv.s;
        }
    }
    __syncthreads();
#pragma unroll
    for (int t = 0; t < 4; ++t) {
        int rl = t * 4 + quad;
        int row = rbase + rl;
        uint4 q = *(const uint4*)(smw + rl * GPAD + mn * 8);
        *(uint4*)(Yu + (size_t)row * NF + mn * 8) = q;
        float g = dinv[row];
        uint4 qs;
        qs.x = pack2h(g * h_lo(q.x), g * h_hi(q.x));
        qs.y = pack2h(g * h_lo(q.y), g * h_hi(q.y));
        qs.z = pack2h(g * h_lo(q.z), g * h_hi(q.z));
        qs.w = pack2h(g * h_lo(q.w), g * h_hi(q.w));
        *(uint4*)(Ys + (size_t)row * NF + mn * 8) = qs;
    }
}

// ---------------------------------------------------------------------------
// APPNP step on f16 scaled state hs[v] = dinv[v]*h[v]:
//   A = sum_{e in row v} hs[col_e]   (packed v_pk_add_f16 — 1 instr / 2 feats)
//   h_new = 0.9*dinv[v]*A + 0.1*x0[v]
//   mode 0: out = dinv*h_new (f16) | mode 1: out = relu(h_new) (bf16, GEMM2 in)
//   mode 2: relu + fused pair projection -> puv
// One 64-lane wave per node; uint2/lane, 2 edges per 512 B gather instr;
// fixed 8-edge round-up batches; dummy slots gather the zeroed row NN.
// f16 accumulation. This is the best-measured configuration (830.7 µs, r10);
// at the session's structural floor: ~90 MB/step compulsory cross-XCD L2
// refill (measured r11/r12) at ~2.6 TB/s effective = ~35 µs/step.
// ---------------------------------------------------------------------------
__global__ __launch_bounds__(256) void appnp_h_k(const unsigned short* __restrict__ hs,
                                                 const unsigned short* __restrict__ x0,
                                                 const float* __restrict__ dinv,
                                                 unsigned short* __restrict__ out,
                                                 const int* __restrict__ row_ptr,
                                                 const int* __restrict__ cols,
                                                 int mode,
                                                 const float* __restrict__ W3,
                                                 float4* __restrict__ puv) {
    int wid = (blockIdx.x * 256 + threadIdx.x) >> 6;
    int lane = threadIdx.x & 63;
    if (wid >= NN) return;
    int half = lane >> 5, li = lane & 31;
    int beg = row_ptr[wid], end = row_ptr[wid + 1];
    h2 a01; a01.x = (_Float16)0.f; a01.y = (_Float16)0.f;
    h2 a23 = a01;
    for (int e = beg; e < end; e += 64) {
        int m = end - e;
        if (m > 64) m = 64;
        int c = (lane < m) ? cols[e + lane] : NN;  // NN = zero row
        for (int j = 0; j < m; j += 8) {
            int c0 = __shfl(c, j + half, 64);
            int c1 = __shfl(c, j + 2 + half, 64);
            int c2 = __shfl(c, j + 4 + half, 64);
            int c3 = __shfl(c, j + 6 + half, 64);
            uint2 q0 = *((const uint2*)(hs + (size_t)c0 * NF) + li);
            uint2 q1 = *((const uint2*)(hs + (size_t)c1 * NF) + li);
            uint2 q2 = *((const uint2*)(hs + (size_t)c2 * NF) + li);
            uint2 q3 = *((const uint2*)(hs + (size_t)c3 * NF) + li);
            a01 += (u2h2(q0.x) + u2h2(q1.x)) + (u2h2(q2.x) + u2h2(q3.x));
            a23 += (u2h2(q0.y) + u2h2(q1.y)) + (u2h2(q2.y) + u2h2(q3.y));
        }
    }
    a01 += u2h2((unsigned)__shfl_xor((int)h22u(a01), 32, 64));
    a23 += u2h2((unsigned)__shfl_xor((int)h22u(a23), 32, 64));
    if (half != 0) return;
    float g = dinv[wid];
    float s9 = 0.9f * g;
    uint2 xq = *((const uint2*)(x0 + (size_t)wid * NF) + li);
    float h0 = s9 * (float)a01.x + 0.1f * h_lo(xq.x);
    float h1 = s9 * (float)a01.y + 0.1f * h_hi(xq.x);
    float h2v = s9 * (float)a23.x + 0.1f * h_lo(xq.y);
    float h3 = s9 * (float)a23.y + 0.1f * h_hi(xq.y);
    if (mode == 0) {
        uint2 oq;
        oq.x = pack2h(g * h0, g * h1);
        oq.y = pack2h(g * h2v, g * h3);
        *((uint2*)(out + (size_t)wid * NF) + li) = oq;
    } else {
        h0 = fmaxf(h0, 0.f); h1 = fmaxf(h1, 0.f);
        h2v = fmaxf(h2v, 0.f); h3 = fmaxf(h3, 0.f);
        if (mode == 1) {
            uint2 oq;
            oq.x = pack2bf(h0, h1);
            oq.y = pack2bf(h2v, h3);
            *((uint2*)(out + (size_t)wid * NF) + li) = oq;
        } else {
            int fb = li * 4;
            float4 wu0 = *(const float4*)(W3 + fb);
            float4 wv0 = *(const float4*)(W3 + 128 + fb);
            float4 wu1 = *(const float4*)(W3 + 256 + fb);
            float4 wv1 = *(const float4*)(W3 + 384 + fb);
            float du0 = h0 * wu0.x + h1 * wu0.y + h2v * wu0.z + h3 * wu0.w;
            float du1 = h0 * wu1.x + h1 * wu1.y + h2v * wu1.z + h3 * wu1.w;
            float dv0 = h0 * wv0.x + h1 * wv0.y + h2v * wv0.z + h3 * wv0.w;
            float dv1 = h0 * wv1.x + h1 * wv1.y + h2v * wv1.z + h3 * wv1.w;
#pragma unroll
            for (int off = 1; off < 32; off <<= 1) {
                du0 += __shfl_xor(du0, off, 64);
                du1 += __shfl_xor(du1, off, 64);
                dv0 += __shfl_xor(dv0, off, 64);
                dv1 += __shfl_xor(dv1, off, 64);
            }
            if (li == 0) puv[wid] = make_float4(du0, du1, dv0, dv1);
        }
    }
}

// ---------------------------------------------------------------------------
// Pair head from precomputed projections: one thread per pair.
// ---------------------------------------------------------------------------
__global__ __launch_bounds__(256) void pair2_k(const float4* __restrict__ puv,
                                               const int2* __restrict__ index,
                                               const float* __restrict__ b3,
                                               float* __restrict__ outp) {
    int p = blockIdx.x * 256 + threadIdx.x;
    if (p >= NP) return;
    int2 uv = index[p];
    float4 a = puv[uv.x];
    float4 b = puv[uv.y];
    float s0 = a.x + b.z + b3[0];
    float s1 = a.y + b.w + b3[1];
    float m = fmaxf(s0, s1);
    float lse = m + logf(expf(s0 - m) + expf(s1 - m));
    *(float2*)(outp + (size_t)p * 2) = make_float2(s0 - lse, s1 - lse);
}

// ---------------------------------------------------------------------------
// Launch
// ---------------------------------------------------------------------------
extern "C" void kernel_launch(void* const* d_in, const int* in_sizes, int n_in,
                              void* d_out, int out_size, void* d_ws, size_t ws_size,
                              hipStream_t stream) {
    const float* x  = (const float*)d_in[0];
    const int* ei   = (const int*)d_in[1];
    const int* idx  = (const int*)d_in[2];
    const float* W1 = (const float*)d_in[3];
    const float* b1 = (const float*)d_in[4];
    const float* W2 = (const float*)d_in[5];
    const float* b2 = (const float*)d_in[6];
    const float* W3 = (const float*)d_in[7];
    const float* b3 = (const float*)d_in[8];
    float* out = (float*)d_out;

    char* ws = (char*)d_ws;
    size_t off = 0;
    auto alloc = [&](size_t bytes) -> void* {
        void* p = ws + off;
        off = (off + bytes + 255) & ~(size_t)255;
        return p;
    };
    const size_t HROWS = (size_t)(NN + 1) * NF;  // +1: zero dummy row
    int*   cnt     = (int*)  alloc(NN * sizeof(int));
    float* dinv    = (float*)alloc(NN * sizeof(float));
    int*   row_ptr = (int*)  alloc((NN + 1) * sizeof(int));
    int*   bsum    = (int*)  alloc(NBLK * sizeof(int));
    int*   boff    = (int*)  alloc(NBLK * sizeof(int));
    int*   gtail   = (int*)  alloc(NBK * sizeof(int));
    int2*  gbk     = (int2*) alloc((size_t)NBK * BKCAP * sizeof(int2));  // 8 MB
    int*   cols    = (int*)  alloc((size_t)NEDGE_TOT * sizeof(int));
    float4* puv    = (float4*)alloc((size_t)NN * sizeof(float4));
    unsigned short* Wb1 = (unsigned short*)alloc(128 * 128 * 2);
    unsigned short* Wb2 = (unsigned short*)alloc(128 * 128 * 2);
    unsigned short* Yu1 = (unsigned short*)alloc(HROWS * 2);
    unsigned short* Ys1 = (unsigned short*)alloc(HROWS * 2);
    unsigned short* Yu2 = (unsigned short*)alloc(HROWS * 2);
    unsigned short* Ys2 = (unsigned short*)alloc(HROWS * 2);
    unsigned short* HA  = (unsigned short*)alloc(HROWS * 2);
    unsigned short* HB  = (unsigned short*)alloc(HROWS * 2);
    unsigned short* Hrelu = (unsigned short*)alloc((size_t)NN * NF * 2);

    const int gN    = (NN + 255) / 256;
    const int gE    = (NE + 255) / 256;
    const int gBin  = (NEDGE_TOT + EPB - 1) / EPB;
    const int gGemm = (NN + 63) / 64;            // wave per 16 rows
    const int gStep = (NN * 64 + 255) / 256;     // 64-lane wave per node
    const int gPair = (NP + 255) / 256;          // thread per pair

    // ---- weights + gcn_norm + binned CSR ----
    cast_w_k<<<8, 256, 0, stream>>>(W1, Wb1);
    cast_w_k<<<8, 256, 0, stream>>>(W2, Wb2);
    zero_k<<<1, 256, 0, stream>>>(Ys1, Ys2, HA, HB, gtail);
    init_cnt_k<<<gN, 256, 0, stream>>>(cnt);
    count_k<<<gE, 256, 0, stream>>>(ei, cnt);
    scan_reduce_k<<<NBLK, 256, 0, stream>>>(cnt, bsum, dinv);
    scan_bsums_k<<<1, 256, 0, stream>>>(bsum, boff);
    scan_down_k<<<NBLK, 256, 0, stream>>>(cnt, boff, row_ptr);
    bin_k<<<gBin, 256, 0, stream>>>(ei, gtail, gbk);
    build_k<<<NBK, 256, 0, stream>>>(row_ptr, gtail, gbk, cols);

    // ---- layer 1 ----
    gemm_mfma_k<true><<<gGemm, 256, 0, stream>>>(x, Wb1, b1, dinv, Yu1, Ys1, NN);
    {
        const unsigned short* cur = Ys1;
        for (int k = 0; k < 10; ++k) {
            unsigned short* dst = (k == 9) ? Hrelu : ((k & 1) ? HB : HA);
            appnp_h_k<<<gStep, 256, 0, stream>>>(cur, Yu1, dinv, dst, row_ptr,
                                                 cols, (k == 9) ? 1 : 0, W3, puv);
            cur = dst;
        }
    }
    // ---- layer 2 ----
    gemm_mfma_k<false><<<gGemm, 256, 0, stream>>>(Hrelu, Wb2, b2, dinv, Yu2, Ys2, NN);
    {
        const unsigned short* cur = Ys2;
        for (int k = 0; k < 10; ++k) {
            unsigned short* dst = (k & 1) ? HB : HA;
            appnp_h_k<<<gStep, 256, 0, stream>>>(cur, Yu2, dinv, dst, row_ptr,
                                                 cols, (k == 9) ? 2 : 0, W3, puv);
            cur = dst;
        }
    }
    // ---- pair head ----
    pair2_k<<<gPair, 256, 0, stream>>>(puv, (const int2*)idx, b3, out);
}